// Round 3
// baseline (527.692 us; speedup 1.0000x reference)
//
#include <hip/hip_runtime.h>

#define MAXB 64

typedef float floatx4 __attribute__((ext_vector_type(4)));

// Kernel 1: bone transform chain. One block.
//  - threads 0..B-1 build rotation matrices R_i from normalized quats (parallel)
//  - threads 0..B-1 precompute b_i = rel_i[:3] @ Rt_parent rows (parallel)
//  - thread 0 runs the 64-step scalar scan t4_i = b_i + rel_i[3]*t4_parent
//  - threads 0..B-1 emit M_i (row-vector convention) to d_out's T section
//  - threads 0..nScales-1 copy pose_bone_scales passthrough
// NOTE: scale (pose_bone_scales * initial_scales) provably never affects the
// outputs: the reference appends the UNSCALED M to transforms_scaled too, so
// pose_bone_initial_scales / scale_index are dead inputs and pose_bone_scales
// is a pure passthrough.
__global__ void bones_kernel(const float* __restrict__ q_in,     // [B,4]
                             const float* __restrict__ scales,   // passthrough
                             const float* __restrict__ offset,   // [3]
                             const float* __restrict__ rel,      // [B,4]
                             const int*   __restrict__ parents,  // [B]
                             float* __restrict__ outT,           // [B,16]
                             float* __restrict__ outScales,
                             int B, int nScales) {
    __shared__ float sR[MAXB][9];   // R row-major (r00..r22)
    __shared__ float sB[MAXB][4];   // precomputed b_i, a_i=rel[3] in [3]
    __shared__ float sT4[MAXB][4];
    const int tid = threadIdx.x;

    if (tid < B) {
        float w = q_in[tid*4+0], x = q_in[tid*4+1], y = q_in[tid*4+2], z = q_in[tid*4+3];
        float n = sqrtf(w*w + x*x + y*y + z*z);
        w /= n; x /= n; y /= n; z /= n;
        sR[tid][0] = 1.f - 2.f*(y*y + z*z);   // r00
        sR[tid][1] = 2.f*(x*y - w*z);         // r01
        sR[tid][2] = 2.f*(x*z + w*y);         // r02
        sR[tid][3] = 2.f*(x*y + w*z);         // r10
        sR[tid][4] = 1.f - 2.f*(x*x + z*z);   // r11
        sR[tid][5] = 2.f*(y*z - w*x);         // r12
        sR[tid][6] = 2.f*(x*z - w*y);         // r20
        sR[tid][7] = 2.f*(y*z + w*x);         // r21
        sR[tid][8] = 1.f - 2.f*(x*x + y*y);   // r22
    }
    __syncthreads();

    if (tid < B) {
        int p = parents[tid];
        if (p >= 0) {
            float r0 = rel[tid*4+0], r1 = rel[tid*4+1], r2 = rel[tid*4+2];
            // t4_c[j] = sum_k rel[k]*M_p[k][j]; M_p[k][j] = R_p[j][k] (k<3)
            sB[tid][0] = r0*sR[p][0] + r1*sR[p][1] + r2*sR[p][2];
            sB[tid][1] = r0*sR[p][3] + r1*sR[p][4] + r2*sR[p][5];
            sB[tid][2] = r0*sR[p][6] + r1*sR[p][7] + r2*sR[p][8];
            sB[tid][3] = rel[tid*4+3];
        }
    }
    __syncthreads();

    if (tid == 0) {
        for (int i = 0; i < B; ++i) {
            int p = parents[i];
            if (p < 0) {
                sT4[i][0] = rel[i*4+0] + offset[0];
                sT4[i][1] = rel[i*4+1] + offset[1];
                sT4[i][2] = rel[i*4+2] + offset[2];
                sT4[i][3] = 1.0f;
            } else {
                float a = sB[i][3];
                sT4[i][0] = sB[i][0] + a * sT4[p][0];
                sT4[i][1] = sB[i][1] + a * sT4[p][1];
                sT4[i][2] = sB[i][2] + a * sT4[p][2];
                sT4[i][3] = a * sT4[p][3];
            }
        }
    }
    __syncthreads();

    if (tid < B) {
        // M row r, col c (r,c<3) = Rt[r][c] = R[c][r]; row 3 = t4; col 3 = 0
        float* o = outT + tid*16;
        o[0]  = sR[tid][0]; o[1]  = sR[tid][3]; o[2]  = sR[tid][6]; o[3]  = 0.f;
        o[4]  = sR[tid][1]; o[5]  = sR[tid][4]; o[6]  = sR[tid][7]; o[7]  = 0.f;
        o[8]  = sR[tid][2]; o[9]  = sR[tid][5]; o[10] = sR[tid][8]; o[11] = 0.f;
        o[12] = sT4[tid][0]; o[13] = sT4[tid][1]; o[14] = sT4[tid][2]; o[15] = sT4[tid][3];
    }
    if (tid < nScales) outScales[tid] = scales[tid];
}

// Kernel 2: LBS reduce. out[v][j] = sum_b sum_i vbi[b][v][i] * T[b][i][j], j<3.
// Two vertices per thread (independent load chains -> more MLP); 16B
// non-temporal loads over the vertex-contiguous dim (coalesced, streaming);
// T broadcast from LDS (wave-uniform reads -> bank broadcast, conflict-free).
__global__ void __launch_bounds__(256)
lbs_kernel(const floatx4* __restrict__ vbi, // [B, NV] float4
           const float* __restrict__ T,     // [B,16]
           float* __restrict__ out,         // [NV,3]
           int B, int NV) {
    __shared__ float sT[MAXB * 16];
    for (int i = threadIdx.x; i < B * 16; i += blockDim.x) sT[i] = T[i];
    __syncthreads();

    const int v0 = blockIdx.x * (blockDim.x * 2) + threadIdx.x;
    const int v1 = v0 + blockDim.x;
    const bool ok0 = v0 < NV;
    const bool ok1 = v1 < NV;
    if (!ok0) return;

    float a0 = 0.f, a1 = 0.f, a2 = 0.f;
    float b0 = 0.f, b1 = 0.f, b2 = 0.f;
    const floatx4* p0 = vbi + v0;
    const floatx4* p1 = vbi + v1;

    if (ok1) {
        #pragma unroll 4
        for (int b = 0; b < B; ++b) {
            const size_t off = (size_t)b * NV;
            floatx4 t0 = __builtin_nontemporal_load(p0 + off);
            floatx4 t1 = __builtin_nontemporal_load(p1 + off);
            const float* m = &sT[b * 16];
            a0 += t0.x*m[0] + t0.y*m[4] + t0.z*m[8]  + t0.w*m[12];
            a1 += t0.x*m[1] + t0.y*m[5] + t0.z*m[9]  + t0.w*m[13];
            a2 += t0.x*m[2] + t0.y*m[6] + t0.z*m[10] + t0.w*m[14];
            b0 += t1.x*m[0] + t1.y*m[4] + t1.z*m[8]  + t1.w*m[12];
            b1 += t1.x*m[1] + t1.y*m[5] + t1.z*m[9]  + t1.w*m[13];
            b2 += t1.x*m[2] + t1.y*m[6] + t1.z*m[10] + t1.w*m[14];
        }
    } else {
        #pragma unroll 4
        for (int b = 0; b < B; ++b) {
            floatx4 t0 = __builtin_nontemporal_load(p0 + (size_t)b * NV);
            const float* m = &sT[b * 16];
            a0 += t0.x*m[0] + t0.y*m[4] + t0.z*m[8]  + t0.w*m[12];
            a1 += t0.x*m[1] + t0.y*m[5] + t0.z*m[9]  + t0.w*m[13];
            a2 += t0.x*m[2] + t0.y*m[6] + t0.z*m[10] + t0.w*m[14];
        }
    }

    __builtin_nontemporal_store(a0, &out[(size_t)v0*3 + 0]);
    __builtin_nontemporal_store(a1, &out[(size_t)v0*3 + 1]);
    __builtin_nontemporal_store(a2, &out[(size_t)v0*3 + 2]);
    if (ok1) {
        __builtin_nontemporal_store(b0, &out[(size_t)v1*3 + 0]);
        __builtin_nontemporal_store(b1, &out[(size_t)v1*3 + 1]);
        __builtin_nontemporal_store(b2, &out[(size_t)v1*3 + 2]);
    }
}

extern "C" void kernel_launch(void* const* d_in, const int* in_sizes, int n_in,
                              void* d_out, int out_size, void* d_ws, size_t ws_size,
                              hipStream_t stream) {
    // Input order per setup_inputs(): 0..3 images/mask (unused by geometry),
    // 4 quats, 5 scales, 6 offset, 7 rel_t, 8 initial_scales (dead),
    // 9 vertices_bone_inverted, 10 bone_parents, 11 scale_index (dead).
    const float*   q       = (const float*)d_in[4];
    const float*   scales  = (const float*)d_in[5];
    const float*   offset  = (const float*)d_in[6];
    const float*   rel     = (const float*)d_in[7];
    const floatx4* vbi     = (const floatx4*)d_in[9];
    const int*     parents = (const int*)d_in[10];

    const int B  = in_sizes[4] / 4;              // 64
    const int NV = in_sizes[9] / (B * 4);        // 400000
    const int nScales = in_sizes[5];             // 96

    float* out       = (float*)d_out;            // verts [NV,3]
    float* outT      = out + (size_t)NV * 3;     // T [B,4,4]
    float* outScales = outT + (size_t)B * 16;    // scales passthrough

    bones_kernel<<<1, 256, 0, stream>>>(q, scales, offset, rel, parents,
                                        outT, outScales, B, nScales);

    const int threads = 256;
    const int vertsPerBlock = threads * 2;
    const int blocks  = (NV + vertsPerBlock - 1) / vertsPerBlock;
    lbs_kernel<<<blocks, threads, 0, stream>>>(vbi, outT, out, B, NV);
}